// Round 18
// baseline (220.057 us; speedup 1.0000x reference)
//
#include <hip/hip_runtime.h>

// B=4 S=2048 C=512 H=8 D=64 G=32 (group size 16 channels), EPS=1e-3
// Pipeline (5 dispatches):
//   prep    : fused {transpose-cvt w_qkv, transpose-cvt w_proj, gn partial sums}
//   gn_norm : reduce slice-partials, normalize+affine -> bf16
//   gemm_qkv: global_load_lds staging; C^T-trick epilogue for q/k (packed ushort4 stores)
//   attn    : R17 (95.7us verified): BK=256, vf register-hoist
//   gemm_proj: global_load_lds staging; C^T-trick epilogue (float4 stores/residual)

typedef short bf16x8 __attribute__((ext_vector_type(8)));
typedef float f32x4 __attribute__((ext_vector_type(4)));

__device__ __forceinline__ unsigned short f2bf(float f) {
  union { float f; unsigned u; } a; a.f = f;
  unsigned u = a.u;
  u += 0x7fffu + ((u >> 16) & 1u);   // RNE
  return (unsigned short)(u >> 16);
}

__device__ __forceinline__ float fast_exp2(float x) {
  return __builtin_amdgcn_exp2f(x);   // v_exp_f32
}

__device__ __forceinline__ unsigned pk2_trunc(float a, float b) {
  return (__builtin_bit_cast(unsigned, a) >> 16) |
         (__builtin_bit_cast(unsigned, b) & 0xffff0000u);
}

__device__ __forceinline__ void load_lds16(const unsigned short* g, unsigned short* l) {
  __builtin_amdgcn_global_load_lds(
      (const __attribute__((address_space(1))) unsigned int*)g,
      (__attribute__((address_space(3))) unsigned int*)l, 16, 0, 0);
}

// ---------------- prep: transposes + gn partial sums, horizontally fused ----------------
__global__ __launch_bounds__(256) void prep_kernel(const float* __restrict__ w_qkv,
                                                   const float* __restrict__ w_proj,
                                                   const float* __restrict__ x,
                                                   unsigned short* __restrict__ wqkv_t,
                                                   unsigned short* __restrict__ wproj_t,
                                                   float* __restrict__ stats_part) {
  __shared__ float sh[32][33];
  const int bid = blockIdx.x, t = threadIdx.x;
  if (bid < 1024) {
    const float* src; unsigned short* dst; int K = 512, N, n0, k0;
    if (bid < 768) { src = w_qkv; dst = wqkv_t; N = 1536; n0 = (bid % 48) * 32; k0 = (bid / 48) * 32; }
    else { const int id2 = bid - 768; src = w_proj; dst = wproj_t; N = 512; n0 = (id2 % 16) * 32; k0 = (id2 / 16) * 32; }
    const int r = t >> 3, c4 = (t & 7) * 4;
    float4 v = *(const float4*)(src + (size_t)(k0 + r) * N + n0 + c4);
    sh[r][c4] = v.x; sh[r][c4 + 1] = v.y; sh[r][c4 + 2] = v.z; sh[r][c4 + 3] = v.w;
    __syncthreads();
    ushort4 o;
    o.x = f2bf(sh[c4][r]);
    o.y = f2bf(sh[c4 + 1][r]);
    o.z = f2bf(sh[c4 + 2][r]);
    o.w = f2bf(sh[c4 + 3][r]);
    *(ushort4*)(dst + (size_t)(n0 + r) * K + k0 + c4) = o;
  } else {
    const int id3 = bid - 1024;
    const int bg = id3 >> 3, sl = id3 & 7;
    const int b = bg >> 5, g = bg & 31;
    const float* xb = x + (size_t)b * (2048 * 512) + (size_t)sl * 256 * 512 + g * 16;
    float sum = 0.f, ss = 0.f;
    for (int i = t; i < 1024; i += 256) {
      const int s = i >> 2, part = i & 3;
      const float4 v = *(const float4*)(xb + (size_t)s * 512 + part * 4);
      sum += v.x + v.y + v.z + v.w;
      ss  += v.x * v.x + v.y * v.y + v.z * v.z + v.w * v.w;
    }
#pragma unroll
    for (int m = 1; m < 64; m <<= 1) {
      sum += __shfl_xor(sum, m, 64);
      ss  += __shfl_xor(ss, m, 64);
    }
    const int wid = t >> 6;
    if ((t & 63) == 0) { sh[0][wid * 2] = sum; sh[0][wid * 2 + 1] = ss; }
    __syncthreads();
    if (t == 0) {
      stats_part[sl * 256 + bg * 2]     = sh[0][0] + sh[0][2] + sh[0][4] + sh[0][6];
      stats_part[sl * 256 + bg * 2 + 1] = sh[0][1] + sh[0][3] + sh[0][5] + sh[0][7];
    }
  }
}

// ---------------- normalize + affine -> bf16 ----------------
__global__ __launch_bounds__(256) void gn_norm_kernel(const float* __restrict__ x,
                                                      const float* __restrict__ gamma,
                                                      const float* __restrict__ beta,
                                                      const float* __restrict__ stats_part,
                                                      unsigned short* __restrict__ xn) {
  __shared__ float smean[32], srstd[32];
  const size_t idx = ((size_t)blockIdx.x * 256 + threadIdx.x) * 8;
  const int b = (int)(idx >> 20);
  if (threadIdx.x < 32) {
    const int g = threadIdx.x;
    float S = 0.f, Q = 0.f;
#pragma unroll
    for (int sl = 0; sl < 8; ++sl) {
      S += stats_part[sl * 256 + (b * 32 + g) * 2];
      Q += stats_part[sl * 256 + (b * 32 + g) * 2 + 1];
    }
    const float mean = S * (1.f / 32768.f);
    smean[g] = mean;
    srstd[g] = rsqrtf(Q * (1.f / 32768.f) - mean * mean + 1e-3f);
  }
  __syncthreads();
  const int c0 = (int)(idx & 511);
  const int g = c0 >> 4;
  const float mean = smean[g];
  const float rstd = srstd[g];
  float4 v0 = *(const float4*)(x + idx);
  float4 v1 = *(const float4*)(x + idx + 4);
  float4 g0 = *(const float4*)(gamma + c0);
  float4 g1 = *(const float4*)(gamma + c0 + 4);
  float4 be0 = *(const float4*)(beta + c0);
  float4 be1 = *(const float4*)(beta + c0 + 4);
  ushort4 o0, o1;
  o0.x = f2bf((v0.x - mean) * rstd * g0.x + be0.x);
  o0.y = f2bf((v0.y - mean) * rstd * g0.y + be0.y);
  o0.z = f2bf((v0.z - mean) * rstd * g0.z + be0.z);
  o0.w = f2bf((v0.w - mean) * rstd * g0.w + be0.w);
  o1.x = f2bf((v1.x - mean) * rstd * g1.x + be1.x);
  o1.y = f2bf((v1.y - mean) * rstd * g1.y + be1.y);
  o1.z = f2bf((v1.z - mean) * rstd * g1.z + be1.z);
  o1.w = f2bf((v1.w - mean) * rstd * g1.w + be1.w);
  *(ushort4*)(xn + idx) = o0;
  *(ushort4*)(xn + idx + 4) = o1;
}

// ---------------- QKV GEMM: C^T trick for q/k blocks (y<8), packed stores ----------------
__global__ __launch_bounds__(256) void gemm_qkv_kernel(const unsigned short* __restrict__ xn,
                                                       const unsigned short* __restrict__ wt,
                                                       unsigned short* __restrict__ qb,
                                                       unsigned short* __restrict__ kb,
                                                       unsigned short* __restrict__ vt) {
  __shared__ unsigned short As[128][32];
  __shared__ unsigned short Bs[128][32];
  const int m0 = blockIdx.x * 128, n0 = blockIdx.y * 128;
  const bool isV = (blockIdx.y >= 8);           // block-uniform (128-tile within one third)
  const int tid = threadIdx.x, lane = tid & 63, wid = tid >> 6;
  const int quad = lane >> 4, l15 = lane & 15;
  const int wm = (wid >> 1) * 64, wn = (wid & 1) * 64;
  const int srow = tid >> 2, sc8 = (tid & 3) * 8;
  f32x4 acc[4][4];
#pragma unroll
  for (int i = 0; i < 4; ++i)
#pragma unroll
    for (int j = 0; j < 4; ++j) acc[i][j] = 0.f;
  for (int k0 = 0; k0 < 512; k0 += 32) {
    __syncthreads();
    load_lds16(xn + (size_t)(m0 + srow) * 512 + k0 + sc8,        &As[srow][sc8]);
    load_lds16(xn + (size_t)(m0 + srow + 64) * 512 + k0 + sc8,   &As[srow + 64][sc8]);
    load_lds16(wt + (size_t)(n0 + srow) * 512 + k0 + sc8,        &Bs[srow][sc8]);
    load_lds16(wt + (size_t)(n0 + srow + 64) * 512 + k0 + sc8,   &Bs[srow + 64][sc8]);
    __syncthreads();
    bf16x8 af[4], bfr[4];
#pragma unroll
    for (int mt = 0; mt < 4; ++mt) af[mt] = *(const bf16x8*)(&As[wm + mt * 16 + l15][quad * 8]);
#pragma unroll
    for (int nt = 0; nt < 4; ++nt) bfr[nt] = *(const bf16x8*)(&Bs[wn + nt * 16 + l15][quad * 8]);
    if (isV) {
#pragma unroll
      for (int mt = 0; mt < 4; ++mt)
#pragma unroll
        for (int nt = 0; nt < 4; ++nt)
          acc[mt][nt] = __builtin_amdgcn_mfma_f32_16x16x32_bf16(af[mt], bfr[nt], acc[mt][nt], 0, 0, 0);
    } else {
      // swapped operands -> C^T: lane holds 4 consecutive f for fixed s
#pragma unroll
      for (int mt = 0; mt < 4; ++mt)
#pragma unroll
        for (int nt = 0; nt < 4; ++nt)
          acc[mt][nt] = __builtin_amdgcn_mfma_f32_16x16x32_bf16(bfr[nt], af[mt], acc[mt][nt], 0, 0, 0);
    }
  }
  const float qscale = 0.125f * 1.44269504088896340736f;
  if (isV) {
    // v: C-layout rows = 4 consecutive s -> packed ushort4 along s into (BH,D,S)
#pragma unroll
    for (int mt = 0; mt < 4; ++mt) {
      const int mbase = m0 + wm + mt * 16 + quad * 4;
      const int b = mbase >> 11, sb = mbase & 2047;
#pragma unroll
      for (int nt = 0; nt < 4; ++nt) {
        const int f = n0 + wn + nt * 16 + l15;
        const int hh = (f >> 6) & 7, d = f & 63;
        const int bh = b * 8 + hh;
        ushort4 o;
        o.x = f2bf(acc[mt][nt][0]); o.y = f2bf(acc[mt][nt][1]);
        o.z = f2bf(acc[mt][nt][2]); o.w = f2bf(acc[mt][nt][3]);
        *(ushort4*)(vt + ((size_t)bh * 64 + d) * 2048 + sb) = o;
      }
    }
  } else {
    // q/k: C^T layout -> lane has s = ...+l15 fixed, f = ...+quad*4+r consecutive
    unsigned short* dst = (blockIdx.y < 4) ? qb : kb;
    const float s = (blockIdx.y < 4) ? qscale : 1.0f;
#pragma unroll
    for (int mt = 0; mt < 4; ++mt) {
      const int srow2 = m0 + wm + mt * 16 + l15;
      const int b = srow2 >> 11, sb = srow2 & 2047;
#pragma unroll
      for (int nt = 0; nt < 4; ++nt) {
        const int fbase = n0 + wn + nt * 16 + quad * 4;   // 4 consecutive f, within one head
        const int hh = (fbase >> 6) & 7, d0 = fbase & 63;
        const int bh = b * 8 + hh;
        ushort4 o;
        o.x = f2bf(acc[mt][nt][0] * s); o.y = f2bf(acc[mt][nt][1] * s);
        o.z = f2bf(acc[mt][nt][2] * s); o.w = f2bf(acc[mt][nt][3] * s);
        *(ushort4*)(dst + ((size_t)bh * 2048 + sb) * 64 + d0) = o;
      }
    }
  }
}

// ---------------- flash attention: R17 exact (95.7us measured) ----------------
__global__ __launch_bounds__(256, 2) void attn_kernel(const unsigned short* __restrict__ qg,
                                                      const unsigned short* __restrict__ kg,
                                                      const unsigned short* __restrict__ vtg,
                                                      unsigned short* __restrict__ xattn) {
  __shared__ unsigned short Vt[64][260];      // V^T [d][256 s_k], pad 260: 33,280 B
  __shared__ unsigned short Ps[4][16][132];   // per-wave P slab (cols 0..127 used): 16,896 B
  const int bh = blockIdx.x & 31;
  const int b = bh >> 3, h = bh & 7;
  const int q0 = (blockIdx.x >> 5) * 128;
  const int tid = threadIdx.x, wid = tid >> 6, lane = tid & 63;
  const int quad = lane >> 4, l15 = lane & 15;
  const size_t base = (size_t)bh * (2048 * 64);

  bf16x8 qf[2][2];
#pragma unroll
  for (int rt = 0; rt < 2; ++rt)
#pragma unroll
    for (int kt = 0; kt < 2; ++kt)
      qf[rt][kt] = *(const bf16x8*)(qg + base +
                    (size_t)(q0 + wid * 32 + rt * 16 + l15) * 64 + kt * 32 + quad * 8);

  f32x4 accO[2][4];
  float l_i[2] = {0.f, 0.f};
#pragma unroll
  for (int rt = 0; rt < 2; ++rt)
#pragma unroll
    for (int nt = 0; nt < 4; ++nt) accO[rt][nt] = 0.f;

  for (int k0 = 0; k0 < 2048; k0 += 256) {
    __syncthreads();                          // all waves done reading prev Vt
    for (int i = tid; i < 2048; i += 256) {   // stage 64x256 V^T tile
      const int d = i >> 5, c8 = (i & 31) * 8;
      *(uint4*)(&Vt[d][c8]) = *(const uint4*)(vtg + ((size_t)bh * 64 + d) * 2048 + k0 + c8);
    }

#pragma unroll
    for (int half = 0; half < 2; ++half) {
      const int kh = k0 + half * 128;
      f32x4 accS[2][8];
#pragma unroll
      for (int rt = 0; rt < 2; ++rt)
#pragma unroll
        for (int ct = 0; ct < 8; ++ct) accS[rt][ct] = 0.f;
#pragma unroll
      for (int kt = 0; kt < 2; ++kt) {
        bf16x8 kf[8];
#pragma unroll
        for (int ct = 0; ct < 8; ++ct)
          kf[ct] = *(const bf16x8*)(kg + base +
                    (size_t)(kh + ct * 16 + l15) * 64 + kt * 32 + quad * 8);
#pragma unroll
        for (int ct = 0; ct < 8; ++ct) {
          accS[0][ct] = __builtin_amdgcn_mfma_f32_16x16x32_bf16(kf[ct], qf[0][kt], accS[0][ct], 0, 0, 0);
          accS[1][ct] = __builtin_amdgcn_mfma_f32_16x16x32_bf16(kf[ct], qf[1][kt], accS[1][ct], 0, 0, 0);
        }
      }

      // softmax rt0 -> Ps
      {
        float rs = 0.f;
#pragma unroll
        for (int ct = 0; ct < 8; ++ct) {
          const float p0 = fast_exp2(accS[0][ct][0]);
          const float p1 = fast_exp2(accS[0][ct][1]);
          const float p2 = fast_exp2(accS[0][ct][2]);
          const float p3 = fast_exp2(accS[0][ct][3]);
          rs += (p0 + p1) + (p2 + p3);
          uint2 pk; pk.x = pk2_trunc(p0, p1); pk.y = pk2_trunc(p2, p3);
          *(uint2*)(&Ps[wid][l15][ct * 16 + quad * 4]) = pk;
        }
        rs += __shfl_xor(rs, 16, 64);
        rs += __shfl_xor(rs, 32, 64);
        l_i[0] += rs;
      }

      if (half == 0) __syncthreads();         // Vt tile ready

      // vf register-hoist (shared across both rt)
      bf16x8 vf[16];
#pragma unroll
      for (int kt2 = 0; kt2 < 4; ++kt2)
#pragma unroll
        for (int nt = 0; nt < 4; ++nt)
          vf[kt2 * 4 + nt] = *(const bf16x8*)(&Vt[nt * 16 + l15][half * 128 + kt2 * 32 + quad * 8]);

      // PV rt0
#pragma unroll
      for (int kt2 = 0; kt2 < 4; ++kt2) {
        bf16x8 pf = *(const bf16x8*)(&Ps[wid][l15][kt2 * 32 + quad * 8]);
#pragma unroll
        for (int nt = 0; nt < 4; ++nt)
          accO[0][nt] = __builtin_amdgcn_mfma_f32_16x16x32_bf16(pf, vf[kt2 * 4 + nt], accO[0][nt], 0, 0, 0);
      }

      // softmax rt1 -> Ps (overwrite; wave-local in-order DS)
      {
        float rs = 0.f;
#pragma unroll
        for (int ct = 0; ct < 8; ++ct) {
          const float p0 = fast_exp2(accS[1][ct][0]);
          const float p1 = fast_exp2(accS[1][ct][1]);
          const float p2 = fast_exp2(accS[1][ct][2]);
          const float p3 = fast_exp2(accS[1][ct][3]);
          rs += (p0 + p1) + (p2 + p3);
          uint2 pk; pk.x = pk2_trunc(p0, p1); pk.y = pk2_trunc(p2, p3);
          *(uint2*)(&Ps[wid][l15][ct * 16 + quad * 4]) = pk;
        }
        rs += __shfl_xor(rs, 16, 64);
        rs += __shfl_xor(rs, 32, 64);
        l_i[1] += rs;
      }

      // PV rt1 (vf regs reused)
#pragma unroll
      for (int kt2 = 0; kt2 < 4; ++kt2) {
        bf16x8 pf = *(const bf16x8*)(&Ps[wid][l15][kt2 * 32 + quad * 8]);
#pragma unroll
        for (int nt = 0; nt < 4; ++nt)
          accO[1][nt] = __builtin_amdgcn_mfma_f32_16x16x32_bf16(pf, vf[kt2 * 4 + nt], accO[1][nt], 0, 0, 0);
      }
    }
  }

  // epilogue
#pragma unroll
  for (int rt = 0; rt < 2; ++rt) {
    float linv[4];
#pragma unroll
    for (int r = 0; r < 4; ++r) linv[r] = 1.f / __shfl(l_i[rt], quad * 4 + r, 64);
#pragma unroll
    for (int nt = 0; nt < 4; ++nt)
#pragma unroll
      for (int r = 0; r < 4; ++r) {
        const int row = q0 + wid * 32 + rt * 16 + quad * 4 + r;
        const int d = nt * 16 + l15;
        xattn[((size_t)b * 2048 + row) * 512 + h * 64 + d] = f2bf(accO[rt][nt][r] * linv[r]);
      }
  }
}

// ---------------- proj GEMM: C^T trick -> float4 stores + float4 residual ----------------
__global__ __launch_bounds__(256) void gemm_proj_kernel(const unsigned short* __restrict__ xa,
                                                        const unsigned short* __restrict__ wt,
                                                        const float* __restrict__ x,
                                                        const float* __restrict__ bp,
                                                        float* __restrict__ out) {
  __shared__ unsigned short As[128][32];
  __shared__ unsigned short Bs[128][32];
  const int m0 = blockIdx.x * 128, n0 = blockIdx.y * 128;
  const int tid = threadIdx.x, lane = tid & 63, wid = tid >> 6;
  const int quad = lane >> 4, l15 = lane & 15;
  const int wm = (wid >> 1) * 64, wn = (wid & 1) * 64;
  const int srow = tid >> 2, sc8 = (tid & 3) * 8;
  f32x4 acc[4][4];
#pragma unroll
  for (int i = 0; i < 4; ++i)
#pragma unroll
    for (int j = 0; j < 4; ++j) acc[i][j] = 0.f;
  for (int k0 = 0; k0 < 512; k0 += 32) {
    __syncthreads();
    load_lds16(xa + (size_t)(m0 + srow) * 512 + k0 + sc8,        &As[srow][sc8]);
    load_lds16(xa + (size_t)(m0 + srow + 64) * 512 + k0 + sc8,   &As[srow + 64][sc8]);
    load_lds16(wt + (size_t)(n0 + srow) * 512 + k0 + sc8,        &Bs[srow][sc8]);
    load_lds16(wt + (size_t)(n0 + srow + 64) * 512 + k0 + sc8,   &Bs[srow + 64][sc8]);
    __syncthreads();
    bf16x8 af[4], bfr[4];
#pragma unroll
    for (int mt = 0; mt < 4; ++mt) af[mt] = *(const bf16x8*)(&As[wm + mt * 16 + l15][quad * 8]);
#pragma unroll
    for (int nt = 0; nt < 4; ++nt) bfr[nt] = *(const bf16x8*)(&Bs[wn + nt * 16 + l15][quad * 8]);
#pragma unroll
    for (int mt = 0; mt < 4; ++mt)
#pragma unroll
      for (int nt = 0; nt < 4; ++nt)
        acc[mt][nt] = __builtin_amdgcn_mfma_f32_16x16x32_bf16(bfr[nt], af[mt], acc[mt][nt], 0, 0, 0);
  }
  // C^T epilogue: lane has m = ...+l15 fixed, c = ...+quad*4+r consecutive -> float4
#pragma unroll
  for (int mt = 0; mt < 4; ++mt) {
    const int m = m0 + wm + mt * 16 + l15;
#pragma unroll
    for (int nt = 0; nt < 4; ++nt) {
      const int cbase = n0 + wn + nt * 16 + quad * 4;
      const float4 xr = *(const float4*)(x + (size_t)m * 512 + cbase);
      const float4 bv = *(const float4*)(bp + cbase);
      float4 o;
      o.x = acc[mt][nt][0] + bv.x + xr.x;
      o.y = acc[mt][nt][1] + bv.y + xr.y;
      o.z = acc[mt][nt][2] + bv.z + xr.z;
      o.w = acc[mt][nt][3] + bv.w + xr.w;
      *(float4*)(out + (size_t)m * 512 + cbase) = o;
    }
  }
}

extern "C" void kernel_launch(void* const* d_in, const int* in_sizes, int n_in,
                              void* d_out, int out_size, void* d_ws, size_t ws_size,
                              hipStream_t stream) {
  (void)in_sizes; (void)n_in; (void)out_size; (void)ws_size;
  const float* x      = (const float*)d_in[0];
  const float* gamma  = (const float*)d_in[1];
  const float* beta   = (const float*)d_in[2];
  const float* w_qkv  = (const float*)d_in[3];
  const float* w_proj = (const float*)d_in[4];
  const float* b_proj = (const float*)d_in[5];
  float* out = (float*)d_out;

  char* ws = (char*)d_ws;
  unsigned short* xn      = (unsigned short*)(ws);              //  8 MB
  unsigned short* qb      = (unsigned short*)(ws + 8388608);    //  8 MB
  unsigned short* kb      = (unsigned short*)(ws + 16777216);   //  8 MB
  unsigned short* vt      = (unsigned short*)(ws + 25165824);   //  8 MB (BH,D,S)
  unsigned short* xattn   = (unsigned short*)(ws + 33554432);   //  8 MB
  unsigned short* wqkv_t  = (unsigned short*)(ws + 41943040);   //  1.5 MB (1536x512)
  unsigned short* wproj_t = (unsigned short*)(ws + 43515904);   //  0.5 MB (512x512)
  float* stats_part       = (float*)(ws + 44040192);            //  8 KB

  prep_kernel<<<2048, 256, 0, stream>>>(w_qkv, w_proj, x, wqkv_t, wproj_t, stats_part);
  gn_norm_kernel<<<2048, 256, 0, stream>>>(x, gamma, beta, stats_part, xn);
  gemm_qkv_kernel<<<dim3(64, 12), 256, 0, stream>>>(xn, wqkv_t, qb, kb, vt);
  attn_kernel<<<512, 256, 0, stream>>>(qb, kb, vt, xattn);
  gemm_proj_kernel<<<dim3(64, 4), 256, 0, stream>>>(xattn, wproj_t, x, b_proj, out);
}

// Round 19
// 213.701 us; speedup vs baseline: 1.0297x; 1.0297x over previous
//
#include <hip/hip_runtime.h>

// B=4 S=2048 C=512 H=8 D=64 G=32 (group size 16 channels), EPS=1e-3
// Pipeline (5 dispatches) — R17 configuration (214.2us verified best):
//   prep    : fused {transpose-cvt w_qkv, transpose-cvt w_proj, gn partial sums}
//   gn_norm : reduce slice-partials, normalize+affine -> bf16
//   gemm_qkv: global_load_lds staging; coalesced scalar q/k + packed V epilogue
//   attn    : BK=256, single Ps slab, QK interleaved, vf register-hoist
//   gemm_proj: global_load_lds staging; coalesced scalar epilogue + bias + residual

typedef short bf16x8 __attribute__((ext_vector_type(8)));
typedef float f32x4 __attribute__((ext_vector_type(4)));

__device__ __forceinline__ unsigned short f2bf(float f) {
  union { float f; unsigned u; } a; a.f = f;
  unsigned u = a.u;
  u += 0x7fffu + ((u >> 16) & 1u);   // RNE
  return (unsigned short)(u >> 16);
}

__device__ __forceinline__ float fast_exp2(float x) {
  return __builtin_amdgcn_exp2f(x);   // v_exp_f32
}

__device__ __forceinline__ unsigned pk2_trunc(float a, float b) {
  return (__builtin_bit_cast(unsigned, a) >> 16) |
         (__builtin_bit_cast(unsigned, b) & 0xffff0000u);
}

__device__ __forceinline__ void load_lds16(const unsigned short* g, unsigned short* l) {
  __builtin_amdgcn_global_load_lds(
      (const __attribute__((address_space(1))) unsigned int*)g,
      (__attribute__((address_space(3))) unsigned int*)l, 16, 0, 0);
}

// ---------------- prep: transposes + gn partial sums, horizontally fused ----------------
__global__ __launch_bounds__(256) void prep_kernel(const float* __restrict__ w_qkv,
                                                   const float* __restrict__ w_proj,
                                                   const float* __restrict__ x,
                                                   unsigned short* __restrict__ wqkv_t,
                                                   unsigned short* __restrict__ wproj_t,
                                                   float* __restrict__ stats_part) {
  __shared__ float sh[32][33];
  const int bid = blockIdx.x, t = threadIdx.x;
  if (bid < 1024) {
    const float* src; unsigned short* dst; int K = 512, N, n0, k0;
    if (bid < 768) { src = w_qkv; dst = wqkv_t; N = 1536; n0 = (bid % 48) * 32; k0 = (bid / 48) * 32; }
    else { const int id2 = bid - 768; src = w_proj; dst = wproj_t; N = 512; n0 = (id2 % 16) * 32; k0 = (id2 / 16) * 32; }
    const int r = t >> 3, c4 = (t & 7) * 4;
    float4 v = *(const float4*)(src + (size_t)(k0 + r) * N + n0 + c4);
    sh[r][c4] = v.x; sh[r][c4 + 1] = v.y; sh[r][c4 + 2] = v.z; sh[r][c4 + 3] = v.w;
    __syncthreads();
    ushort4 o;
    o.x = f2bf(sh[c4][r]);
    o.y = f2bf(sh[c4 + 1][r]);
    o.z = f2bf(sh[c4 + 2][r]);
    o.w = f2bf(sh[c4 + 3][r]);
    *(ushort4*)(dst + (size_t)(n0 + r) * K + k0 + c4) = o;
  } else {
    const int id3 = bid - 1024;
    const int bg = id3 >> 3, sl = id3 & 7;
    const int b = bg >> 5, g = bg & 31;
    const float* xb = x + (size_t)b * (2048 * 512) + (size_t)sl * 256 * 512 + g * 16;
    float sum = 0.f, ss = 0.f;
    for (int i = t; i < 1024; i += 256) {
      const int s = i >> 2, part = i & 3;
      const float4 v = *(const float4*)(xb + (size_t)s * 512 + part * 4);
      sum += v.x + v.y + v.z + v.w;
      ss  += v.x * v.x + v.y * v.y + v.z * v.z + v.w * v.w;
    }
#pragma unroll
    for (int m = 1; m < 64; m <<= 1) {
      sum += __shfl_xor(sum, m, 64);
      ss  += __shfl_xor(ss, m, 64);
    }
    const int wid = t >> 6;
    if ((t & 63) == 0) { sh[0][wid * 2] = sum; sh[0][wid * 2 + 1] = ss; }
    __syncthreads();
    if (t == 0) {
      stats_part[sl * 256 + bg * 2]     = sh[0][0] + sh[0][2] + sh[0][4] + sh[0][6];
      stats_part[sl * 256 + bg * 2 + 1] = sh[0][1] + sh[0][3] + sh[0][5] + sh[0][7];
    }
  }
}

// ---------------- normalize + affine -> bf16 ----------------
__global__ __launch_bounds__(256) void gn_norm_kernel(const float* __restrict__ x,
                                                      const float* __restrict__ gamma,
                                                      const float* __restrict__ beta,
                                                      const float* __restrict__ stats_part,
                                                      unsigned short* __restrict__ xn) {
  __shared__ float smean[32], srstd[32];
  const size_t idx = ((size_t)blockIdx.x * 256 + threadIdx.x) * 8;
  const int b = (int)(idx >> 20);
  if (threadIdx.x < 32) {
    const int g = threadIdx.x;
    float S = 0.f, Q = 0.f;
#pragma unroll
    for (int sl = 0; sl < 8; ++sl) {
      S += stats_part[sl * 256 + (b * 32 + g) * 2];
      Q += stats_part[sl * 256 + (b * 32 + g) * 2 + 1];
    }
    const float mean = S * (1.f / 32768.f);
    smean[g] = mean;
    srstd[g] = rsqrtf(Q * (1.f / 32768.f) - mean * mean + 1e-3f);
  }
  __syncthreads();
  const int c0 = (int)(idx & 511);
  const int g = c0 >> 4;
  const float mean = smean[g];
  const float rstd = srstd[g];
  float4 v0 = *(const float4*)(x + idx);
  float4 v1 = *(const float4*)(x + idx + 4);
  float4 g0 = *(const float4*)(gamma + c0);
  float4 g1 = *(const float4*)(gamma + c0 + 4);
  float4 be0 = *(const float4*)(beta + c0);
  float4 be1 = *(const float4*)(beta + c0 + 4);
  ushort4 o0, o1;
  o0.x = f2bf((v0.x - mean) * rstd * g0.x + be0.x);
  o0.y = f2bf((v0.y - mean) * rstd * g0.y + be0.y);
  o0.z = f2bf((v0.z - mean) * rstd * g0.z + be0.z);
  o0.w = f2bf((v0.w - mean) * rstd * g0.w + be0.w);
  o1.x = f2bf((v1.x - mean) * rstd * g1.x + be1.x);
  o1.y = f2bf((v1.y - mean) * rstd * g1.y + be1.y);
  o1.z = f2bf((v1.z - mean) * rstd * g1.z + be1.z);
  o1.w = f2bf((v1.w - mean) * rstd * g1.w + be1.w);
  *(ushort4*)(xn + idx) = o0;
  *(ushort4*)(xn + idx + 4) = o1;
}

// ---------------- QKV GEMM: R15/R17 epilogue (coalesced) ----------------
__global__ __launch_bounds__(256) void gemm_qkv_kernel(const unsigned short* __restrict__ xn,
                                                       const unsigned short* __restrict__ wt,
                                                       unsigned short* __restrict__ qb,
                                                       unsigned short* __restrict__ kb,
                                                       unsigned short* __restrict__ vt) {
  __shared__ unsigned short As[128][32];
  __shared__ unsigned short Bs[128][32];
  const int m0 = blockIdx.x * 128, n0 = blockIdx.y * 128;
  const int tid = threadIdx.x, lane = tid & 63, wid = tid >> 6;
  const int quad = lane >> 4, l15 = lane & 15;
  const int wm = (wid >> 1) * 64, wn = (wid & 1) * 64;
  const int srow = tid >> 2, sc8 = (tid & 3) * 8;
  f32x4 acc[4][4];
#pragma unroll
  for (int i = 0; i < 4; ++i)
#pragma unroll
    for (int j = 0; j < 4; ++j) acc[i][j] = 0.f;
  for (int k0 = 0; k0 < 512; k0 += 32) {
    __syncthreads();
    load_lds16(xn + (size_t)(m0 + srow) * 512 + k0 + sc8,        &As[srow][sc8]);
    load_lds16(xn + (size_t)(m0 + srow + 64) * 512 + k0 + sc8,   &As[srow + 64][sc8]);
    load_lds16(wt + (size_t)(n0 + srow) * 512 + k0 + sc8,        &Bs[srow][sc8]);
    load_lds16(wt + (size_t)(n0 + srow + 64) * 512 + k0 + sc8,   &Bs[srow + 64][sc8]);
    __syncthreads();
    bf16x8 af[4], bfr[4];
#pragma unroll
    for (int mt = 0; mt < 4; ++mt) af[mt] = *(const bf16x8*)(&As[wm + mt * 16 + l15][quad * 8]);
#pragma unroll
    for (int nt = 0; nt < 4; ++nt) bfr[nt] = *(const bf16x8*)(&Bs[wn + nt * 16 + l15][quad * 8]);
#pragma unroll
    for (int mt = 0; mt < 4; ++mt)
#pragma unroll
      for (int nt = 0; nt < 4; ++nt)
        acc[mt][nt] = __builtin_amdgcn_mfma_f32_16x16x32_bf16(af[mt], bfr[nt], acc[mt][nt], 0, 0, 0);
  }
  const float qscale = 0.125f * 1.44269504088896340736f;
#pragma unroll
  for (int mt = 0; mt < 4; ++mt) {
    const int mbase = m0 + wm + mt * 16 + quad * 4;
    const int b = mbase >> 11, sb = mbase & 2047;
#pragma unroll
    for (int nt = 0; nt < 4; ++nt) {
      const int f = n0 + wn + nt * 16 + l15;
      const int which = f >> 9, hh = (f >> 6) & 7, d = f & 63;
      const int bh = b * 8 + hh;
      if (which == 2) {
        ushort4 o;
        o.x = f2bf(acc[mt][nt][0]); o.y = f2bf(acc[mt][nt][1]);
        o.z = f2bf(acc[mt][nt][2]); o.w = f2bf(acc[mt][nt][3]);
        *(ushort4*)(vt + ((size_t)bh * 64 + d) * 2048 + sb) = o;
      } else {
        unsigned short* dst = which == 0 ? qb : kb;
        const float s = which == 0 ? qscale : 1.0f;
#pragma unroll
        for (int r = 0; r < 4; ++r)
          dst[((size_t)bh * 2048 + sb + r) * 64 + d] = f2bf(acc[mt][nt][r] * s);
      }
    }
  }
}

// ---------------- flash attention: R17 exact (95.7us measured) ----------------
__global__ __launch_bounds__(256, 2) void attn_kernel(const unsigned short* __restrict__ qg,
                                                      const unsigned short* __restrict__ kg,
                                                      const unsigned short* __restrict__ vtg,
                                                      unsigned short* __restrict__ xattn) {
  __shared__ unsigned short Vt[64][260];      // V^T [d][256 s_k], pad 260: 33,280 B
  __shared__ unsigned short Ps[4][16][132];   // per-wave P slab (cols 0..127 used): 16,896 B
  const int bh = blockIdx.x & 31;
  const int b = bh >> 3, h = bh & 7;
  const int q0 = (blockIdx.x >> 5) * 128;
  const int tid = threadIdx.x, wid = tid >> 6, lane = tid & 63;
  const int quad = lane >> 4, l15 = lane & 15;
  const size_t base = (size_t)bh * (2048 * 64);

  bf16x8 qf[2][2];
#pragma unroll
  for (int rt = 0; rt < 2; ++rt)
#pragma unroll
    for (int kt = 0; kt < 2; ++kt)
      qf[rt][kt] = *(const bf16x8*)(qg + base +
                    (size_t)(q0 + wid * 32 + rt * 16 + l15) * 64 + kt * 32 + quad * 8);

  f32x4 accO[2][4];
  float l_i[2] = {0.f, 0.f};
#pragma unroll
  for (int rt = 0; rt < 2; ++rt)
#pragma unroll
    for (int nt = 0; nt < 4; ++nt) accO[rt][nt] = 0.f;

  for (int k0 = 0; k0 < 2048; k0 += 256) {
    __syncthreads();                          // all waves done reading prev Vt
    for (int i = tid; i < 2048; i += 256) {   // stage 64x256 V^T tile
      const int d = i >> 5, c8 = (i & 31) * 8;
      *(uint4*)(&Vt[d][c8]) = *(const uint4*)(vtg + ((size_t)bh * 64 + d) * 2048 + k0 + c8);
    }

#pragma unroll
    for (int half = 0; half < 2; ++half) {
      const int kh = k0 + half * 128;
      // QK: both rt interleaved, batched kf shared
      f32x4 accS[2][8];
#pragma unroll
      for (int rt = 0; rt < 2; ++rt)
#pragma unroll
        for (int ct = 0; ct < 8; ++ct) accS[rt][ct] = 0.f;
#pragma unroll
      for (int kt = 0; kt < 2; ++kt) {
        bf16x8 kf[8];
#pragma unroll
        for (int ct = 0; ct < 8; ++ct)
          kf[ct] = *(const bf16x8*)(kg + base +
                    (size_t)(kh + ct * 16 + l15) * 64 + kt * 32 + quad * 8);
#pragma unroll
        for (int ct = 0; ct < 8; ++ct) {
          accS[0][ct] = __builtin_amdgcn_mfma_f32_16x16x32_bf16(kf[ct], qf[0][kt], accS[0][ct], 0, 0, 0);
          accS[1][ct] = __builtin_amdgcn_mfma_f32_16x16x32_bf16(kf[ct], qf[1][kt], accS[1][ct], 0, 0, 0);
        }
      }

      // softmax rt0 -> Ps
      {
        float rs = 0.f;
#pragma unroll
        for (int ct = 0; ct < 8; ++ct) {
          const float p0 = fast_exp2(accS[0][ct][0]);
          const float p1 = fast_exp2(accS[0][ct][1]);
          const float p2 = fast_exp2(accS[0][ct][2]);
          const float p3 = fast_exp2(accS[0][ct][3]);
          rs += (p0 + p1) + (p2 + p3);
          uint2 pk; pk.x = pk2_trunc(p0, p1); pk.y = pk2_trunc(p2, p3);
          *(uint2*)(&Ps[wid][l15][ct * 16 + quad * 4]) = pk;
        }
        rs += __shfl_xor(rs, 16, 64);
        rs += __shfl_xor(rs, 32, 64);
        l_i[0] += rs;
      }

      if (half == 0) __syncthreads();         // Vt tile ready

      // vf register-hoist (shared across both rt)
      bf16x8 vf[16];
#pragma unroll
      for (int kt2 = 0; kt2 < 4; ++kt2)
#pragma unroll
        for (int nt = 0; nt < 4; ++nt)
          vf[kt2 * 4 + nt] = *(const bf16x8*)(&Vt[nt * 16 + l15][half * 128 + kt2 * 32 + quad * 8]);

      // PV rt0
#pragma unroll
      for (int kt2 = 0; kt2 < 4; ++kt2) {
        bf16x8 pf = *(const bf16x8*)(&Ps[wid][l15][kt2 * 32 + quad * 8]);
#pragma unroll
        for (int nt = 0; nt < 4; ++nt)
          accO[0][nt] = __builtin_amdgcn_mfma_f32_16x16x32_bf16(pf, vf[kt2 * 4 + nt], accO[0][nt], 0, 0, 0);
      }

      // softmax rt1 -> Ps (overwrite; wave-local in-order DS)
      {
        float rs = 0.f;
#pragma unroll
        for (int ct = 0; ct < 8; ++ct) {
          const float p0 = fast_exp2(accS[1][ct][0]);
          const float p1 = fast_exp2(accS[1][ct][1]);
          const float p2 = fast_exp2(accS[1][ct][2]);
          const float p3 = fast_exp2(accS[1][ct][3]);
          rs += (p0 + p1) + (p2 + p3);
          uint2 pk; pk.x = pk2_trunc(p0, p1); pk.y = pk2_trunc(p2, p3);
          *(uint2*)(&Ps[wid][l15][ct * 16 + quad * 4]) = pk;
        }
        rs += __shfl_xor(rs, 16, 64);
        rs += __shfl_xor(rs, 32, 64);
        l_i[1] += rs;
      }

      // PV rt1 (vf regs reused)
#pragma unroll
      for (int kt2 = 0; kt2 < 4; ++kt2) {
        bf16x8 pf = *(const bf16x8*)(&Ps[wid][l15][kt2 * 32 + quad * 8]);
#pragma unroll
        for (int nt = 0; nt < 4; ++nt)
          accO[1][nt] = __builtin_amdgcn_mfma_f32_16x16x32_bf16(pf, vf[kt2 * 4 + nt], accO[1][nt], 0, 0, 0);
      }
    }
  }

  // epilogue
#pragma unroll
  for (int rt = 0; rt < 2; ++rt) {
    float linv[4];
#pragma unroll
    for (int r = 0; r < 4; ++r) linv[r] = 1.f / __shfl(l_i[rt], quad * 4 + r, 64);
#pragma unroll
    for (int nt = 0; nt < 4; ++nt)
#pragma unroll
      for (int r = 0; r < 4; ++r) {
        const int row = q0 + wid * 32 + rt * 16 + quad * 4 + r;
        const int d = nt * 16 + l15;
        xattn[((size_t)b * 2048 + row) * 512 + h * 64 + d] = f2bf(accO[rt][nt][r] * linv[r]);
      }
  }
}

// ---------------- proj GEMM: R15/R17 epilogue (coalesced) + bias + residual ----------------
__global__ __launch_bounds__(256) void gemm_proj_kernel(const unsigned short* __restrict__ xa,
                                                        const unsigned short* __restrict__ wt,
                                                        const float* __restrict__ x,
                                                        const float* __restrict__ bp,
                                                        float* __restrict__ out) {
  __shared__ unsigned short As[128][32];
  __shared__ unsigned short Bs[128][32];
  const int m0 = blockIdx.x * 128, n0 = blockIdx.y * 128;
  const int tid = threadIdx.x, lane = tid & 63, wid = tid >> 6;
  const int quad = lane >> 4, l15 = lane & 15;
  const int wm = (wid >> 1) * 64, wn = (wid & 1) * 64;
  const int srow = tid >> 2, sc8 = (tid & 3) * 8;
  f32x4 acc[4][4];
#pragma unroll
  for (int i = 0; i < 4; ++i)
#pragma unroll
    for (int j = 0; j < 4; ++j) acc[i][j] = 0.f;
  for (int k0 = 0; k0 < 512; k0 += 32) {
    __syncthreads();
    load_lds16(xa + (size_t)(m0 + srow) * 512 + k0 + sc8,        &As[srow][sc8]);
    load_lds16(xa + (size_t)(m0 + srow + 64) * 512 + k0 + sc8,   &As[srow + 64][sc8]);
    load_lds16(wt + (size_t)(n0 + srow) * 512 + k0 + sc8,        &Bs[srow][sc8]);
    load_lds16(wt + (size_t)(n0 + srow + 64) * 512 + k0 + sc8,   &Bs[srow + 64][sc8]);
    __syncthreads();
    bf16x8 af[4], bfr[4];
#pragma unroll
    for (int mt = 0; mt < 4; ++mt) af[mt] = *(const bf16x8*)(&As[wm + mt * 16 + l15][quad * 8]);
#pragma unroll
    for (int nt = 0; nt < 4; ++nt) bfr[nt] = *(const bf16x8*)(&Bs[wn + nt * 16 + l15][quad * 8]);
#pragma unroll
    for (int mt = 0; mt < 4; ++mt)
#pragma unroll
      for (int nt = 0; nt < 4; ++nt)
        acc[mt][nt] = __builtin_amdgcn_mfma_f32_16x16x32_bf16(af[mt], bfr[nt], acc[mt][nt], 0, 0, 0);
  }
#pragma unroll
  for (int mt = 0; mt < 4; ++mt)
#pragma unroll
    for (int nt = 0; nt < 4; ++nt)
#pragma unroll
      for (int r = 0; r < 4; ++r) {
        const int m = m0 + wm + mt * 16 + quad * 4 + r;
        const int c = n0 + wn + nt * 16 + l15;
        out[(size_t)m * 512 + c] = acc[mt][nt][r] + bp[c] + x[(size_t)m * 512 + c];
      }
}

extern "C" void kernel_launch(void* const* d_in, const int* in_sizes, int n_in,
                              void* d_out, int out_size, void* d_ws, size_t ws_size,
                              hipStream_t stream) {
  (void)in_sizes; (void)n_in; (void)out_size; (void)ws_size;
  const float* x      = (const float*)d_in[0];
  const float* gamma  = (const float*)d_in[1];
  const float* beta   = (const float*)d_in[2];
  const float* w_qkv  = (const float*)d_in[3];
  const float* w_proj = (const float*)d_in[4];
  const float* b_proj = (const float*)d_in[5];
  float* out = (float*)d_out;

  char* ws = (char*)d_ws;
  unsigned short* xn      = (unsigned short*)(ws);              //  8 MB
  unsigned short* qb      = (unsigned short*)(ws + 8388608);    //  8 MB
  unsigned short* kb      = (unsigned short*)(ws + 16777216);   //  8 MB
  unsigned short* vt      = (unsigned short*)(ws + 25165824);   //  8 MB (BH,D,S)
  unsigned short* xattn   = (unsigned short*)(ws + 33554432);   //  8 MB
  unsigned short* wqkv_t  = (unsigned short*)(ws + 41943040);   //  1.5 MB (1536x512)
  unsigned short* wproj_t = (unsigned short*)(ws + 43515904);   //  0.5 MB (512x512)
  float* stats_part       = (float*)(ws + 44040192);            //  8 KB

  prep_kernel<<<2048, 256, 0, stream>>>(w_qkv, w_proj, x, wqkv_t, wproj_t, stats_part);
  gn_norm_kernel<<<2048, 256, 0, stream>>>(x, gamma, beta, stats_part, xn);
  gemm_qkv_kernel<<<dim3(64, 12), 256, 0, stream>>>(xn, wqkv_t, qb, kb, vt);
  attn_kernel<<<512, 256, 0, stream>>>(qb, kb, vt, xattn);
  gemm_proj_kernel<<<dim3(64, 4), 256, 0, stream>>>(xattn, wproj_t, x, b_proj, out);
}